// Round 1
// baseline (154.165 us; speedup 1.0000x reference)
//
#include <hip/hip_runtime.h>

#define N 8192
#define D 256
#define BM 128
#define BN 128
#define LDA 264   // padded LDS row stride in bf16 elems: 528B -> 2-way bank alias (free)

typedef short short8 __attribute__((ext_vector_type(8)));
typedef float f32x4 __attribute__((ext_vector_type(4)));

__device__ __forceinline__ unsigned short f2bf(float f) {
    unsigned int u = __float_as_uint(f);
    u += 0x7fffu + ((u >> 16) & 1u);   // RNE
    return (unsigned short)(u >> 16);
}
__device__ __forceinline__ float bf2f(unsigned short h) {
    return __uint_as_float(((unsigned int)h) << 16);
}

// Kernel 0: per-row squared norms (of bf16-rounded features, consistent with the
// MFMA Gram) + zero the S/L accumulators (ws is poisoned 0xAA before every call).
__global__ __launch_bounds__(256) void k_sq_init(const float* __restrict__ x,
                                                 float* __restrict__ sq,
                                                 float* __restrict__ Sarr,
                                                 float* __restrict__ Larr) {
    const int wid = threadIdx.x >> 6, lane = threadIdx.x & 63;
    const int row = blockIdx.x * 4 + wid;
    const float4 v = ((const float4*)x)[(size_t)row * (D / 4) + lane];
    float a = bf2f(f2bf(v.x)), b = bf2f(f2bf(v.y));
    float c = bf2f(f2bf(v.z)), d = bf2f(f2bf(v.w));
    float s = a * a + b * b + c * c + d * d;
#pragma unroll
    for (int m = 1; m < 64; m <<= 1) s += __shfl_xor(s, m, 64);
    if (lane == 0) {
        sq[row] = s;
        Sarr[row] = 0.0f;
        Larr[row] = 0.0f;
    }
}

// Kernel 1: tiled bf16-MFMA Gram with fused exp epilogue.
// Block = 128 rows x 2048-col chunk (16 j-tiles of 128). Grid (64, 4).
// Per row accumulate S = sum_j exp(-d2/2T^2), L = sum_j k*ln(k) (ln k = -d2/2T^2, no log needed).
__global__ __launch_bounds__(256) void k_gram(const float* __restrict__ x,
                                              const float* __restrict__ sq,
                                              const float* __restrict__ temp,
                                              float* __restrict__ Sarr,
                                              float* __restrict__ Larr) {
    __shared__ unsigned short As[BM * LDA];
    __shared__ unsigned short Bs[BN * LDA];
    __shared__ float sqB[BN];

    const int tid = threadIdx.x;
    const int rowbase = blockIdx.x * BM;
    const int chunk = blockIdx.y;  // 0..3, each covers 2048 columns
    const float T = temp[0];
    const float inv2T2 = 1.0f / (2.0f * T * T);

    const int wv = tid >> 6;          // wave 0..3, owns rows wv*32..wv*32+31
    const int lane = tid & 63;
    const int q = lane >> 4;          // quad 0..3
    const int c = lane & 15;

    // stage A tile: 128x256 fp32 -> bf16 LDS (once per block)
#pragma unroll
    for (int it = 0; it < 16; ++it) {
        int ch = it * 256 + tid;      // 4096 16B chunks
        int r = ch >> 5, cc = ch & 31;
        const float4* gp = (const float4*)(x + (size_t)(rowbase + r) * D + cc * 8);
        float4 v0 = gp[0], v1 = gp[1];
        short8 p;
        p[0] = (short)f2bf(v0.x); p[1] = (short)f2bf(v0.y);
        p[2] = (short)f2bf(v0.z); p[3] = (short)f2bf(v0.w);
        p[4] = (short)f2bf(v1.x); p[5] = (short)f2bf(v1.y);
        p[6] = (short)f2bf(v1.z); p[7] = (short)f2bf(v1.w);
        *(short8*)(&As[r * LDA + cc * 8]) = p;
    }

    // preload this lane's 8 row norms (rows: wv*32 + tr*16 + q*4 + r)
    float sqr[8];
#pragma unroll
    for (int tr = 0; tr < 2; ++tr)
#pragma unroll
        for (int r = 0; r < 4; ++r)
            sqr[tr * 4 + r] = sq[rowbase + wv * 32 + tr * 16 + q * 4 + r];

    float Sp[8], Lp[8];
#pragma unroll
    for (int i = 0; i < 8; ++i) { Sp[i] = 0.0f; Lp[i] = 0.0f; }

    for (int jt = 0; jt < 16; ++jt) {
        const int colbase = chunk * 2048 + jt * BN;
        __syncthreads();  // protect Bs from previous iter's readers (and A staging on iter 0)
#pragma unroll
        for (int it = 0; it < 16; ++it) {
            int ch = it * 256 + tid;
            int r = ch >> 5, cc = ch & 31;
            const float4* gp = (const float4*)(x + (size_t)(colbase + r) * D + cc * 8);
            float4 v0 = gp[0], v1 = gp[1];
            short8 p;
            p[0] = (short)f2bf(v0.x); p[1] = (short)f2bf(v0.y);
            p[2] = (short)f2bf(v0.z); p[3] = (short)f2bf(v0.w);
            p[4] = (short)f2bf(v1.x); p[5] = (short)f2bf(v1.y);
            p[6] = (short)f2bf(v1.z); p[7] = (short)f2bf(v1.w);
            *(short8*)(&Bs[r * LDA + cc * 8]) = p;
        }
        if (tid < BN) sqB[tid] = sq[colbase + tid];
        __syncthreads();

        // 32x128 Gram sub-block per wave: 2x8 MFMA tiles, K = 256 in 8 steps
        f32x4 acc[2][8];
#pragma unroll
        for (int tr = 0; tr < 2; ++tr)
#pragma unroll
            for (int tc = 0; tc < 8; ++tc)
#pragma unroll
                for (int r = 0; r < 4; ++r) acc[tr][tc][r] = 0.0f;

#pragma unroll
        for (int kk = 0; kk < 8; ++kk) {
            short8 av[2];
#pragma unroll
            for (int tr = 0; tr < 2; ++tr)
                av[tr] = *(const short8*)(&As[(wv * 32 + tr * 16 + c) * LDA + kk * 32 + q * 8]);
            short8 bv[8];
#pragma unroll
            for (int tc = 0; tc < 8; ++tc)
                bv[tc] = *(const short8*)(&Bs[(tc * 16 + c) * LDA + kk * 32 + q * 8]);
#pragma unroll
            for (int tr = 0; tr < 2; ++tr)
#pragma unroll
                for (int tc = 0; tc < 8; ++tc)
                    acc[tr][tc] = __builtin_amdgcn_mfma_f32_16x16x32_bf16(
                        av[tr], bv[tc], acc[tr][tc], 0, 0, 0);
        }

        // fused epilogue: d2 -> exp -> accumulate S, L per row
#pragma unroll
        for (int tr = 0; tr < 2; ++tr)
#pragma unroll
            for (int tc = 0; tc < 8; ++tc) {
                float sc = sqB[tc * 16 + c];
#pragma unroll
                for (int r = 0; r < 4; ++r) {
                    float g = acc[tr][tc][r];
                    float d2 = fmaxf(sqr[tr * 4 + r] + sc - 2.0f * g, 0.0f);
                    float t = -d2 * inv2T2;   // = ln k
                    float e = __expf(t);      // = k
                    Sp[tr * 4 + r] += e;
                    Lp[tr * 4 + r] += e * t;
                }
            }
    }

    // reduce across the 16 column-lanes sharing each row (lane bits 0..3)
#pragma unroll
    for (int m = 1; m <= 8; m <<= 1)
#pragma unroll
        for (int i = 0; i < 8; ++i) {
            Sp[i] += __shfl_xor(Sp[i], m, 64);
            Lp[i] += __shfl_xor(Lp[i], m, 64);
        }
    if (c == 0) {
#pragma unroll
        for (int i = 0; i < 8; ++i) {
            int row = rowbase + wv * 32 + (i >> 2) * 16 + q * 4 + (i & 3);
            atomicAdd(&Sarr[row], Sp[i]);
            atomicAdd(&Larr[row], Lp[i]);
        }
    }
}

// Kernel 2: entropy = log(S) - L/S ; control = sigmoid(-(H - target)/T)
__global__ __launch_bounds__(256) void k_ctrl(const float* __restrict__ Sarr,
                                              const float* __restrict__ Larr,
                                              const float* __restrict__ target,
                                              const float* __restrict__ temp,
                                              float* __restrict__ ctrl,
                                              float* __restrict__ out) {
    const int r = blockIdx.x * 256 + threadIdx.x;
    float S = Sarr[r], L = Larr[r];
    float H = __logf(S) - L / S;
    float z = (H - target[0]) / temp[0];
    float cs = 1.0f / (1.0f + __expf(z));
    ctrl[r] = cs;
    out[(size_t)N * D + r] = cs;  // control_signal section of d_out
}

// Kernel 3: controlled_features = features * control[row]
__global__ __launch_bounds__(256) void k_scale(const float* __restrict__ x,
                                               const float* __restrict__ ctrl,
                                               float* __restrict__ out) {
    const size_t i = (size_t)blockIdx.x * 256 + threadIdx.x;  // float4 index
    float4 v = ((const float4*)x)[i];
    float cs = ctrl[i >> 6];  // 64 float4 per row
    float4 o;
    o.x = v.x * cs; o.y = v.y * cs; o.z = v.z * cs; o.w = v.w * cs;
    ((float4*)out)[i] = o;
}

extern "C" void kernel_launch(void* const* d_in, const int* in_sizes, int n_in,
                              void* d_out, int out_size, void* d_ws, size_t ws_size,
                              hipStream_t stream) {
    const float* x = (const float*)d_in[0];       // features [4,2048,256]
    const float* target = (const float*)d_in[7];  // target_entropy [1]
    const float* temp = (const float*)d_in[8];    // temperature [1]
    float* out = (float*)d_out;

    float* wsf = (float*)d_ws;   // 4*N floats = 128 KB of scratch
    float* sq = wsf;
    float* Sarr = wsf + N;
    float* Larr = wsf + 2 * N;
    float* ctrl = wsf + 3 * N;

    k_sq_init<<<N / 4, 256, 0, stream>>>(x, sq, Sarr, Larr);
    k_gram<<<dim3(N / BM, 4), 256, 0, stream>>>(x, sq, temp, Sarr, Larr);
    k_ctrl<<<N / 256, 256, 0, stream>>>(Sarr, Larr, target, temp, ctrl, out);
    k_scale<<<(N * D / 4) / 256, 256, 0, stream>>>(x, ctrl, out);
}

// Round 2
// 126.093 us; speedup vs baseline: 1.2226x; 1.2226x over previous
//
#include <hip/hip_runtime.h>

#define N 8192
#define D 256
#define BM 128          // rows per block
#define BN 64           // B-cols per LDS tile
#define CH 512          // cols per block (grid.y chunk)
#define NJT (CH / BN)   // 8 j-tiles per block

typedef short short8 __attribute__((ext_vector_type(8)));
typedef float f32x4 __attribute__((ext_vector_type(4)));

__device__ __forceinline__ unsigned short f2bf(float f) {
    unsigned int u = __float_as_uint(f);
    u += 0x7fffu + ((u >> 16) & 1u);   // RNE
    return (unsigned short)(u >> 16);
}
__device__ __forceinline__ float bf2f(unsigned short h) {
    return __uint_as_float(((unsigned int)h) << 16);
}

// async global->LDS, 16B per lane; dst is wave-uniform base, lane i lands at dst + i*16
#define GLDS16(g, l) __builtin_amdgcn_global_load_lds(                      \
    (const __attribute__((address_space(1))) void*)(g),                     \
    (__attribute__((address_space(3))) void*)(l), 16, 0, 0)

// Kernel 0: fp32 -> bf16 pre-conversion (one wave per row) + row squared norms
// (of the bf16-rounded values, consistent with the MFMA Gram) + zero S/L.
__global__ __launch_bounds__(256) void k_cvt(const float* __restrict__ x,
                                             unsigned short* __restrict__ xb,
                                             float* __restrict__ sq,
                                             float* __restrict__ Sarr,
                                             float* __restrict__ Larr) {
    const int wv = threadIdx.x >> 6, lane = threadIdx.x & 63;
    const int row = blockIdx.x * 4 + wv;
    const float4 v = ((const float4*)x)[(size_t)row * 64 + lane];
    unsigned short pa = f2bf(v.x), pb = f2bf(v.y), pc = f2bf(v.z), pd = f2bf(v.w);
    float a = bf2f(pa), b = bf2f(pb), c = bf2f(pc), d = bf2f(pd);
    float s = a * a + b * b + c * c + d * d;
    ((ushort4*)xb)[(size_t)row * 64 + lane] = make_ushort4(pa, pb, pc, pd);
#pragma unroll
    for (int m = 1; m < 64; m <<= 1) s += __shfl_xor(s, m, 64);
    if (lane == 0) {
        sq[row] = s;
        Sarr[row] = 0.0f;
        Larr[row] = 0.0f;
    }
}

// Kernel 1: Gram via bf16 MFMA. A (128 rows x K=256) held in registers per wave
// (32 rows each). B streamed through a single 32 KB LDS tile (64 cols x 256)
// staged with global_load_lds; 16B-chunk XOR swizzle (slot = chunk ^ (row&7))
// applied on the staging SOURCE address so fragment reads are bank-balanced.
// Fused epilogue: d2 -> exp -> accumulate S = sum k, L = sum k*ln k.
__global__ __launch_bounds__(256, 3) void k_gram(const unsigned short* __restrict__ xb,
                                                 const float* __restrict__ sq,
                                                 const float* __restrict__ temp,
                                                 float* __restrict__ Sarr,
                                                 float* __restrict__ Larr) {
    __shared__ unsigned short Bs[BN * D];   // 32 KB, swizzled at 16B granularity

    const int tid = threadIdx.x;
    const int wv = tid >> 6, lane = tid & 63;
    const int q = lane >> 4, c = lane & 15;
    const int rowbase = blockIdx.x * BM;
    const int colbase0 = blockIdx.y * CH;
    const float T = temp[0];
    const float inv2T2 = 1.0f / (2.0f * T * T);

    // A fragments in registers: wave wv owns rows rowbase + wv*32 .. +31
    short8 av[2][8];
#pragma unroll
    for (int tr = 0; tr < 2; ++tr) {
        const unsigned short* ap = xb + (size_t)(rowbase + wv * 32 + tr * 16 + c) * D;
#pragma unroll
        for (int kk = 0; kk < 8; ++kk)
            av[tr][kk] = *(const short8*)(ap + kk * 32 + q * 8);
    }

    float sqr[8];
#pragma unroll
    for (int tr = 0; tr < 2; ++tr)
#pragma unroll
        for (int r = 0; r < 4; ++r)
            sqr[tr * 4 + r] = sq[rowbase + wv * 32 + tr * 16 + q * 4 + r];

    // per-lane LDS read swizzle precompute (per col-tile)
    int rofs[4], rx3[4];
#pragma unroll
    for (int tc = 0; tc < 4; ++tc) {
        int r = tc * 16 + c;
        rofs[tc] = r * D;      // shorts
        rx3[tc] = r & 7;
    }

    // staging-source lane decomposition
    const int seg0 = wv * 8;        // each wave stages 8 x 1KB segments
    const int rhalf = lane >> 5, slot = lane & 31;

    float Sp[8], Lp[8];
#pragma unroll
    for (int i = 0; i < 8; ++i) { Sp[i] = 0.0f; Lp[i] = 0.0f; }

    for (int jt = 0; jt < NJT; ++jt) {
        const int colbase = colbase0 + jt * BN;
        __syncthreads();   // previous tile's readers done
#pragma unroll
        for (int i = 0; i < 8; ++i) {
            int seg = seg0 + i;
            int row = seg * 2 + rhalf;              // B-col index 0..63
            int g = slot ^ (row & 7);               // source chunk for this slot
            GLDS16(xb + (size_t)(colbase + row) * D + g * 8, Bs + seg * 512);
        }
        __syncthreads();   // staging complete (vmcnt drained at barrier)

        f32x4 acc[2][4];
#pragma unroll
        for (int tr = 0; tr < 2; ++tr)
#pragma unroll
            for (int tc = 0; tc < 4; ++tc)
#pragma unroll
                for (int r = 0; r < 4; ++r) acc[tr][tc][r] = 0.0f;

#pragma unroll
        for (int kk = 0; kk < 8; ++kk) {
            short8 bv[4];
#pragma unroll
            for (int tc = 0; tc < 4; ++tc)
                bv[tc] = *(const short8*)(Bs + rofs[tc] + (((4 * kk + q) ^ rx3[tc]) << 3));
#pragma unroll
            for (int tr = 0; tr < 2; ++tr)
#pragma unroll
                for (int tc = 0; tc < 4; ++tc)
                    acc[tr][tc] = __builtin_amdgcn_mfma_f32_16x16x32_bf16(
                        av[tr][kk], bv[tc], acc[tr][tc], 0, 0, 0);
        }

        float scq[4];
#pragma unroll
        for (int tc = 0; tc < 4; ++tc) scq[tc] = sq[colbase + tc * 16 + c];

#pragma unroll
        for (int tr = 0; tr < 2; ++tr)
#pragma unroll
            for (int tc = 0; tc < 4; ++tc)
#pragma unroll
                for (int r = 0; r < 4; ++r) {
                    float g = acc[tr][tc][r];
                    float d2 = fmaxf(sqr[tr * 4 + r] + scq[tc] - 2.0f * g, 0.0f);
                    float t = -d2 * inv2T2;   // = ln k
                    float e = __expf(t);      // = k
                    Sp[tr * 4 + r] += e;
                    Lp[tr * 4 + r] += e * t;
                }
    }

    // reduce across the 16 column-lanes sharing each row (lane bits 0..3)
#pragma unroll
    for (int m = 1; m <= 8; m <<= 1)
#pragma unroll
        for (int i = 0; i < 8; ++i) {
            Sp[i] += __shfl_xor(Sp[i], m, 64);
            Lp[i] += __shfl_xor(Lp[i], m, 64);
        }
    if (c == 0) {
#pragma unroll
        for (int i = 0; i < 8; ++i) {
            int row = rowbase + wv * 32 + (i >> 2) * 16 + q * 4 + (i & 3);
            atomicAdd(&Sarr[row], Sp[i]);
            atomicAdd(&Larr[row], Lp[i]);
        }
    }
}

// Kernel 2: entropy = log(S) - L/S ; control = sigmoid(-(H - target)/T)
__global__ __launch_bounds__(256) void k_ctrl(const float* __restrict__ Sarr,
                                              const float* __restrict__ Larr,
                                              const float* __restrict__ target,
                                              const float* __restrict__ temp,
                                              float* __restrict__ ctrl,
                                              float* __restrict__ out) {
    const int r = blockIdx.x * 256 + threadIdx.x;
    float S = Sarr[r], L = Larr[r];
    float H = __logf(S) - L / S;
    float z = (H - target[0]) / temp[0];
    float cs = 1.0f / (1.0f + __expf(z));
    ctrl[r] = cs;
    out[(size_t)N * D + r] = cs;  // control_signal section of d_out
}

// Kernel 3: controlled_features = features * control[row]
__global__ __launch_bounds__(256) void k_scale(const float* __restrict__ x,
                                               const float* __restrict__ ctrl,
                                               float* __restrict__ out) {
    const size_t i = (size_t)blockIdx.x * 256 + threadIdx.x;  // float4 index
    float4 v = ((const float4*)x)[i];
    float cs = ctrl[i >> 6];  // 64 float4 per row
    float4 o;
    o.x = v.x * cs; o.y = v.y * cs; o.z = v.z * cs; o.w = v.w * cs;
    ((float4*)out)[i] = o;
}

extern "C" void kernel_launch(void* const* d_in, const int* in_sizes, int n_in,
                              void* d_out, int out_size, void* d_ws, size_t ws_size,
                              hipStream_t stream) {
    const float* x = (const float*)d_in[0];       // features [4,2048,256]
    const float* target = (const float*)d_in[7];  // target_entropy [1]
    const float* temp = (const float*)d_in[8];    // temperature [1]
    float* out = (float*)d_out;

    float* wsf = (float*)d_ws;
    float* sq = wsf;
    float* Sarr = wsf + N;
    float* Larr = wsf + 2 * N;
    float* ctrl = wsf + 3 * N;

    // bf16 copy of X: in ws if it fits, else park it in d_out's first 4 MB
    // (d_out is 8.4 MB; k_scale overwrites that region only after k_gram is done)
    const size_t need = 4 * (size_t)N * sizeof(float) + (size_t)N * D * sizeof(unsigned short);
    unsigned short* xb = (ws_size >= need) ? (unsigned short*)(wsf + 4 * N)
                                           : (unsigned short*)d_out;

    k_cvt<<<N / 4, 256, 0, stream>>>(x, xb, sq, Sarr, Larr);
    k_gram<<<dim3(N / BM, N / CH), 256, 0, stream>>>(xb, sq, temp, Sarr, Larr);
    k_ctrl<<<N / 256, 256, 0, stream>>>(Sarr, Larr, target, temp, ctrl, out);
    k_scale<<<(N * (D / 4)) / 256, 256, 0, stream>>>(x, ctrl, out);
}